// Round 1
// baseline (254.081 us; speedup 1.0000x reference)
//
#include <hip/hip_runtime.h>
#include <hip/hip_bf16.h>

// Flash-style fused attention for B=4,H=8,S=2048,D=64 fp32 (bf16 MFMA compute).
// score = qk^T/sqrt(64)+mask ; softmax ; @kv. kv doubles as K and V.
// Layouts per cdna_hip_programming.md §3 (m89/m91/m120-verified):
//  mfma_f32_16x16x32_bf16: A[m=lane&15][k=quad*8+j], B[k=quad*8+j][n=lane&15],
//  C/D: col=lane&15, row=quad*4+reg.

typedef __bf16 bf16;
typedef __attribute__((ext_vector_type(8))) __bf16 bf16x8;
typedef __attribute__((ext_vector_type(4))) __bf16 bf16x4;
typedef __attribute__((ext_vector_type(4))) float floatx4;

#define SLEN 2048
#define DH   64
#define BR   64              // q rows per block (16 per wave)
#define BC   64              // keys per k-iteration
#define NKT  (SLEN / BC)
#define LDT  72              // LDS row stride in bf16 (144 B = 16B-aligned, 2-way banks)
#define LOG2E 1.44269504088896341f

// ---- pre-pass: per-64x64-tile "mask has any nonzero" flags ----
__global__ __launch_bounds__(256) void attn_mask_flags(
    const float* __restrict__ mask, int* __restrict__ flags)
{
    const int kt = blockIdx.x, qt = blockIdx.y;
    const int t = threadIdx.x;
    float acc = 0.f;
#pragma unroll
    for (int i = 0; i < 4; ++i) {
        int f = i * 256 + t;
        int row = f >> 4, c4 = (f & 15) * 4;
        const float4 v = *(const float4*)(mask + (size_t)(qt * BR + row) * SLEN + kt * BC + c4);
        acc = fmaxf(acc, fmaxf(fmaxf(fabsf(v.x), fabsf(v.y)), fmaxf(fabsf(v.z), fabsf(v.w))));
    }
    unsigned long long any = __ballot(acc != 0.f);
    __shared__ int wany[4];
    if ((t & 63) == 0) wany[t >> 6] = (any != 0ull) ? 1 : 0;
    __syncthreads();
    if (t == 0) flags[qt * NKT + kt] = wany[0] | wany[1] | wany[2] | wany[3];
}

// ---- main fused attention ----
__global__ __launch_bounds__(256) void attn_fwd(
    const float* __restrict__ q, const float* __restrict__ kv,
    const float* __restrict__ mask, const int* __restrict__ flags,
    float* __restrict__ out)
{
    __shared__ __align__(16) bf16 Kl[BC * LDT];   // [key][d]  (B-operand for QK^T)
    __shared__ __align__(16) bf16 Vt[DH * LDT];   // [d][key]  (B-operand for PV)
    __shared__ __align__(16) bf16 Pl[BR * LDT];   // [qrow][key] per-wave 16-row slabs

    const int qt = blockIdx.x;
    const int bh = blockIdx.y;
    const int q0 = qt * BR;
    const int t = threadIdx.x;
    const int wave = t >> 6, lane = t & 63;
    const int ln16 = lane & 15, quad = lane >> 4;

    // Q A-fragments in registers, scale = (1/8)*log2e folded in.
    const float qscale = 0.125f * LOG2E;
    bf16x8 aq[2];
    {
        const float* qrow = q + ((size_t)bh * SLEN + q0 + wave * 16 + ln16) * DH;
#pragma unroll
        for (int kc = 0; kc < 2; ++kc) {
            float4 f0 = *(const float4*)(qrow + kc * 32 + quad * 8);
            float4 f1 = *(const float4*)(qrow + kc * 32 + quad * 8 + 4);
            bf16x8 a;
            a[0] = (bf16)(f0.x * qscale); a[1] = (bf16)(f0.y * qscale);
            a[2] = (bf16)(f0.z * qscale); a[3] = (bf16)(f0.w * qscale);
            a[4] = (bf16)(f1.x * qscale); a[5] = (bf16)(f1.y * qscale);
            a[6] = (bf16)(f1.z * qscale); a[7] = (bf16)(f1.w * qscale);
            aq[kc] = a;
        }
    }

    floatx4 o[4];
#pragma unroll
    for (int dt = 0; dt < 4; ++dt) o[dt] = (floatx4){0.f, 0.f, 0.f, 0.f};
    float m_run[4], l_run[4];
#pragma unroll
    for (int r = 0; r < 4; ++r) { m_run[r] = -3.0e38f; l_run[r] = 0.f; }

    const float* kvb = kv + (size_t)bh * SLEN * DH;

    for (int kt = 0; kt < NKT; ++kt) {
        // -- stage kv tile (64 keys x 64 d fp32) -> bf16 LDS, two layouts --
        float4 st[4];
        const float* kvt = kvb + (size_t)kt * BC * DH;
#pragma unroll
        for (int i = 0; i < 4; ++i) {
            int f = i * 256 + t;
            st[i] = *(const float4*)(kvt + (size_t)f * 4);
        }
        __syncthreads();   // all waves done reading previous tile
#pragma unroll
        for (int i = 0; i < 4; ++i) {
            int f = i * 256 + t;
            int key = f >> 4, d4 = (f & 15) * 4;
            bf16 b0 = (bf16)st[i].x, b1 = (bf16)st[i].y, b2 = (bf16)st[i].z, b3 = (bf16)st[i].w;
            *(bf16x4*)&Kl[key * LDT + d4] = (bf16x4){b0, b1, b2, b3};
            Vt[(d4 + 0) * LDT + key] = b0;
            Vt[(d4 + 1) * LDT + key] = b1;
            Vt[(d4 + 2) * LDT + key] = b2;
            Vt[(d4 + 3) * LDT + key] = b3;
        }
        __syncthreads();

        // -- S = Q K^T (already in log2e units) --
        floatx4 s[4];
#pragma unroll
        for (int nt = 0; nt < 4; ++nt) {
            s[nt] = (floatx4){0.f, 0.f, 0.f, 0.f};
#pragma unroll
            for (int kc = 0; kc < 2; ++kc) {
                bf16x8 bk = *(const bf16x8*)&Kl[(ln16 + 16 * nt) * LDT + kc * 32 + quad * 8];
                s[nt] = __builtin_amdgcn_mfma_f32_16x16x32_bf16(aq[kc], bk, s[nt], 0, 0, 0);
            }
        }

        // -- mask add (skipped when the tile is all-zero) --
        if (!flags || flags[qt * NKT + kt]) {
            const float* mrow = mask + (size_t)(q0 + quad * 4) * SLEN + kt * BC + ln16;
#pragma unroll
            for (int r = 0; r < 4; ++r)
#pragma unroll
                for (int nt = 0; nt < 4; ++nt)
                    s[nt][r] += mrow[(size_t)r * SLEN + nt * 16] * LOG2E;
        }

        // -- online softmax (rows quad*4+r; reduce across the 16 lanes of a quad) --
#pragma unroll
        for (int r = 0; r < 4; ++r) {
            float mx = fmaxf(fmaxf(s[0][r], s[1][r]), fmaxf(s[2][r], s[3][r]));
            mx = fmaxf(mx, __shfl_xor(mx, 1));
            mx = fmaxf(mx, __shfl_xor(mx, 2));
            mx = fmaxf(mx, __shfl_xor(mx, 4));
            mx = fmaxf(mx, __shfl_xor(mx, 8));
            float mnew = fmaxf(m_run[r], mx);
            float alpha = exp2f(m_run[r] - mnew);
            m_run[r] = mnew;
            float rs = 0.f;
#pragma unroll
            for (int nt = 0; nt < 4; ++nt) {
                float p = exp2f(s[nt][r] - mnew);
                s[nt][r] = p;
                rs += p;
            }
            rs += __shfl_xor(rs, 1);
            rs += __shfl_xor(rs, 2);
            rs += __shfl_xor(rs, 4);
            rs += __shfl_xor(rs, 8);
            l_run[r] = l_run[r] * alpha + rs;
#pragma unroll
            for (int dt = 0; dt < 4; ++dt) o[dt][r] *= alpha;
        }

        // -- P: C-layout -> A-layout via LDS (wave-private slab) --
#pragma unroll
        for (int nt = 0; nt < 4; ++nt)
#pragma unroll
            for (int r = 0; r < 4; ++r)
                Pl[(wave * 16 + quad * 4 + r) * LDT + ln16 + 16 * nt] = (bf16)s[nt][r];

        // -- O += P V --
#pragma unroll
        for (int kc2 = 0; kc2 < 2; ++kc2) {
            bf16x8 pf = *(const bf16x8*)&Pl[(wave * 16 + ln16) * LDT + kc2 * 32 + quad * 8];
#pragma unroll
            for (int dt = 0; dt < 4; ++dt) {
                bf16x8 vf = *(const bf16x8*)&Vt[(ln16 + 16 * dt) * LDT + kc2 * 32 + quad * 8];
                o[dt] = __builtin_amdgcn_mfma_f32_16x16x32_bf16(pf, vf, o[dt], 0, 0, 0);
            }
        }
    }

    // -- epilogue: divide by l, store fp32 --
#pragma unroll
    for (int r = 0; r < 4; ++r) {
        float inv = 1.0f / l_run[r];
        int qrow = q0 + wave * 16 + quad * 4 + r;
        float* orow = out + ((size_t)bh * SLEN + qrow) * DH;
#pragma unroll
        for (int dt = 0; dt < 4; ++dt)
            orow[ln16 + 16 * dt] = o[dt][r] * inv;
    }
}

extern "C" void kernel_launch(void* const* d_in, const int* in_sizes, int n_in,
                              void* d_out, int out_size, void* d_ws, size_t ws_size,
                              hipStream_t stream)
{
    const float* q    = (const float*)d_in[0];
    const float* kv   = (const float*)d_in[1];
    const float* mask = (const float*)d_in[2];
    float* out = (float*)d_out;

    const int BH = in_sizes[0] / (SLEN * DH);   // 32
    const int NQT = SLEN / BR;                  // 32

    int* flags = nullptr;
    if (ws_size >= (size_t)(NQT * NKT) * sizeof(int)) {
        flags = (int*)d_ws;
        attn_mask_flags<<<dim3(NKT, NQT), 256, 0, stream>>>(mask, flags);
    }
    attn_fwd<<<dim3(NQT, BH), 256, 0, stream>>>(q, kv, mask, flags, out);
}

// Round 2
// 178.015 us; speedup vs baseline: 1.4273x; 1.4273x over previous
//
#include <hip/hip_runtime.h>
#include <hip/hip_bf16.h>
#include <stdint.h>

// Flash attention B=4,H=8,S=2048,D=64 fp32 io, bf16 MFMA compute.
// Round 2: S^T-trick (P stays in registers as a 16x16x16 A-fragment),
// bf16 prepass of kv into ws (both layouts, granule-rotated V^T),
// global_load_lds staging, conflict-free LDS layouts.

typedef __bf16 bf16;
typedef __attribute__((ext_vector_type(8))) __bf16 bf16x8;
typedef __attribute__((ext_vector_type(4))) __bf16 bf16x4;
typedef __attribute__((ext_vector_type(4))) float floatx4;
typedef __attribute__((ext_vector_type(4))) short short4v;

#define SLEN 2048
#define DH   64
#define BR   64
#define BC   64
#define NKT  (SLEN / BC)
#define NQT  (SLEN / BR)
#define BH_N 32
#define LOG2E 1.44269504088896341f

// chunked LDS tile: 8 chunks of (8 rows x 128B) + 64B pad
#define CHB   1088
#define TILEB (8 * CHB)

#define AS1 __attribute__((address_space(1)))
#define AS3 __attribute__((address_space(3)))

static __device__ inline void gload_lds16(const void* g, void* l) {
    __builtin_amdgcn_global_load_lds((const AS1 uint32_t*)g, (AS3 uint32_t*)l, 16, 0, 0);
}

static __device__ inline floatx4 mfma16_bf16(bf16x4 a, bf16x4 b, floatx4 c) {
#if __has_builtin(__builtin_amdgcn_mfma_f32_16x16x16_bf16)
    return __builtin_amdgcn_mfma_f32_16x16x16_bf16(a, b, c, 0, 0, 0);
#else
    union { bf16x4 h; short4v s; } ua, ub;
    ua.h = a; ub.h = b;
    return __builtin_amdgcn_mfma_f32_16x16x16bf16_1k(ua.s, ub.s, c, 0, 0, 0);
#endif
}

// ---- pre-pass A: per-64x64-tile "mask has any nonzero" flags ----
__global__ __launch_bounds__(256) void attn_mask_flags(
    const float* __restrict__ mask, int* __restrict__ flags)
{
    const int kt = blockIdx.x, qt = blockIdx.y;
    const int t = threadIdx.x;
    float acc = 0.f;
#pragma unroll
    for (int i = 0; i < 4; ++i) {
        int f = i * 256 + t;
        int row = f >> 4, c4 = (f & 15) * 4;
        const float4 v = *(const float4*)(mask + (size_t)(qt * BR + row) * SLEN + kt * BC + c4);
        acc = fmaxf(acc, fmaxf(fmaxf(fabsf(v.x), fabsf(v.y)), fmaxf(fabsf(v.z), fabsf(v.w))));
    }
    unsigned long long any = __ballot(acc != 0.f);
    __shared__ int wany[4];
    if ((t & 63) == 0) wany[t >> 6] = (any != 0ull) ? 1 : 0;
    __syncthreads();
    if (t == 0) flags[qt * NKT + kt] = wany[0] | wany[1] | wany[2] | wany[3];
}

// ---- pre-pass B: kv fp32 -> bf16 kvK [bh][key][d] and kvT [bh][d][key-rotated] ----
__global__ __launch_bounds__(256) void kv_prep(
    const float* __restrict__ kv, bf16* __restrict__ kvK, bf16* __restrict__ kvT)
{
    __shared__ bf16 Tl[64 * 72];
    const int kt = blockIdx.x, bh = blockIdx.y;
    const int t = threadIdx.x;
#pragma unroll
    for (int i = 0; i < 4; ++i) {
        int f = i * 256 + t;
        int kl = f >> 4, d4 = (f & 15) * 4;
        size_t gidx = ((size_t)bh * SLEN + kt * 64 + kl) * DH + d4;
        float4 v = *(const float4*)(kv + gidx);
        bf16x4 b; b[0] = (bf16)v.x; b[1] = (bf16)v.y; b[2] = (bf16)v.z; b[3] = (bf16)v.w;
        *(bf16x4*)(kvK + gidx) = b;
        *(bf16x4*)&Tl[kl * 72 + d4] = b;
    }
    __syncthreads();
#pragma unroll
    for (int i = 0; i < 4; ++i) {
        int f = i * 256 + t;
        int d = f >> 4, c = f & 15;
        bf16x4 w;
        w[0] = Tl[(4 * c + 0) * 72 + d];
        w[1] = Tl[(4 * c + 1) * 72 + d];
        w[2] = Tl[(4 * c + 2) * 72 + d];
        w[3] = Tl[(4 * c + 3) * 72 + d];
        int pg = (c + d) & 15;   // granule rotation (bank spread for LDS reads later)
        *(bf16x4*)(kvT + ((size_t)bh * DH + d) * SLEN + kt * 64 + pg * 4) = w;
    }
}

// ---- main fused attention (S^T scheme) ----
__global__ __launch_bounds__(256) void attn_fwd2(
    const float* __restrict__ q, const float* __restrict__ mask,
    const int* __restrict__ flags,
    const bf16* __restrict__ kvK, const bf16* __restrict__ kvT,
    float* __restrict__ out)
{
    __shared__ __align__(16) char Kl[TILEB];   // K tile [key][d], chunked
    __shared__ __align__(16) char Vt[TILEB];   // V^T tile [d][key-rotated], chunked

    const int bh = blockIdx.x;                 // bh fast for XCD/L2 locality
    const int qt = blockIdx.y;
    const int q0 = qt * BR;
    const int t = threadIdx.x;
    const int wave = t >> 6, lane = t & 63;
    const int ln16 = lane & 15, quad = lane >> 4;

    // Q registers: B[k=d=kc*32+quad*8+j][n=row=ln16], scale folded
    const float qscale = 0.125f * LOG2E;
    bf16x8 aq[2];
    {
        const float* qrow = q + ((size_t)bh * SLEN + q0 + wave * 16 + ln16) * DH;
#pragma unroll
        for (int kc = 0; kc < 2; ++kc) {
            float4 f0 = *(const float4*)(qrow + kc * 32 + quad * 8);
            float4 f1 = *(const float4*)(qrow + kc * 32 + quad * 8 + 4);
            bf16x8 a;
            a[0] = (bf16)(f0.x * qscale); a[1] = (bf16)(f0.y * qscale);
            a[2] = (bf16)(f0.z * qscale); a[3] = (bf16)(f0.w * qscale);
            a[4] = (bf16)(f1.x * qscale); a[5] = (bf16)(f1.y * qscale);
            a[6] = (bf16)(f1.z * qscale); a[7] = (bf16)(f1.w * qscale);
            aq[kc] = a;
        }
    }

    floatx4 o[4];
#pragma unroll
    for (int dt = 0; dt < 4; ++dt) o[dt] = (floatx4){0.f, 0.f, 0.f, 0.f};
    float m_run = -3.0e38f, l_run = 0.f;

    const bf16* kvKb = kvK + (size_t)bh * SLEN * DH;
    const bf16* kvTb = kvT + (size_t)bh * DH * SLEN;

    for (int kt = 0; kt < NKT; ++kt) {
        __syncthreads();   // previous tile fully consumed before overwrite
        {
            const bf16* srcK = kvKb + (size_t)kt * BC * DH;
#pragma unroll
            for (int r = 0; r < 2; ++r) {
                int ch = r * 4 + wave;
                gload_lds16(srcK + (size_t)ch * 8 * DH + lane * 8, Kl + ch * CHB);
                int d0 = ch * 8 + (lane >> 3);
                gload_lds16(kvTb + (size_t)d0 * SLEN + kt * BC + (lane & 7) * 8,
                            Vt + ch * CHB);
            }
        }
        __builtin_amdgcn_s_waitcnt(0);
        __syncthreads();

        // S^T = K * Q^T  (D[m=key][n=row]); 4 key-blocks x 2 k-chunks
        floatx4 s[4];
#pragma unroll
        for (int nt = 0; nt < 4; ++nt) {
            int R = 16 * nt + ln16;
            const char* rowp = Kl + (R >> 3) * CHB + (R & 7) * 128;
            bf16x8 k0 = *(const bf16x8*)(rowp + quad * 16);
            bf16x8 k1 = *(const bf16x8*)(rowp + 64 + quad * 16);
            floatx4 acc = (floatx4){0.f, 0.f, 0.f, 0.f};
            acc = __builtin_amdgcn_mfma_f32_16x16x32_bf16(k0, aq[0], acc, 0, 0, 0);
            acc = __builtin_amdgcn_mfma_f32_16x16x32_bf16(k1, aq[1], acc, 0, 0, 0);
            s[nt] = acc;
        }

        // mask add (rows = ln16, keys = 16nt+quad*4+r), skipped when tile all-zero
        if (flags[qt * NKT + kt]) {
            const float* mrow = mask + (size_t)(q0 + wave * 16 + ln16) * SLEN + kt * BC;
#pragma unroll
            for (int nt = 0; nt < 4; ++nt) {
                float4 mv = *(const float4*)(mrow + 16 * nt + quad * 4);
                s[nt][0] += mv.x * LOG2E; s[nt][1] += mv.y * LOG2E;
                s[nt][2] += mv.z * LOG2E; s[nt][3] += mv.w * LOG2E;
            }
        }

        // online softmax: one q-row per lane (row=ln16), reduce over 16 regs + quads
        float tmax = s[0][0];
#pragma unroll
        for (int nt = 0; nt < 4; ++nt)
#pragma unroll
            for (int r = 0; r < 4; ++r) tmax = fmaxf(tmax, s[nt][r]);
        tmax = fmaxf(tmax, __shfl_xor(tmax, 16));
        tmax = fmaxf(tmax, __shfl_xor(tmax, 32));
        float mnew = fmaxf(m_run, tmax);
        unsigned long long grew = __ballot(mnew > m_run);
        float alpha = exp2f(m_run - mnew);
        m_run = mnew;

        float rs = 0.f;
        bf16x4 pf[4];
#pragma unroll
        for (int nt = 0; nt < 4; ++nt) {
#pragma unroll
            for (int r = 0; r < 4; ++r) {
                float p = exp2f(s[nt][r] - mnew);
                rs += p;
                pf[nt][r] = (bf16)p;
            }
        }
        rs += __shfl_xor(rs, 16);
        rs += __shfl_xor(rs, 32);

        if (grew) {   // wave-uniform: some row's max increased
            l_run = l_run * alpha + rs;
            float a0 = __shfl(alpha, quad * 4 + 0);
            float a1 = __shfl(alpha, quad * 4 + 1);
            float a2 = __shfl(alpha, quad * 4 + 2);
            float a3 = __shfl(alpha, quad * 4 + 3);
#pragma unroll
            for (int dt = 0; dt < 4; ++dt) {
                o[dt][0] *= a0; o[dt][1] *= a1; o[dt][2] *= a2; o[dt][3] *= a3;
            }
        } else {
            l_run += rs;
        }

        // O += P V : P is already an A-fragment in registers (pf),
        // V B-fragments are 8B LDS reads (granule-rotated, conflict-free)
        const int vbase = (ln16 >> 3) * CHB + (ln16 & 7) * 128;
#pragma unroll
        for (int nt = 0; nt < 4; ++nt) {
            int pg = (4 * nt + quad + ln16) & 15;
#pragma unroll
            for (int dt = 0; dt < 4; ++dt) {
                bf16x4 vf = *(const bf16x4*)(Vt + vbase + dt * 2 * CHB + pg * 8);
                o[dt] = mfma16_bf16(pf[nt], vf, o[dt]);
            }
        }
    }

    // epilogue: O[row=quad*4+r][d=ln16+16dt], l lives at lane (quad*4+r)
    float l0 = __shfl(l_run, quad * 4 + 0);
    float l1 = __shfl(l_run, quad * 4 + 1);
    float l2 = __shfl(l_run, quad * 4 + 2);
    float l3 = __shfl(l_run, quad * 4 + 3);
    float i0 = 1.f / l0, i1 = 1.f / l1, i2 = 1.f / l2, i3 = 1.f / l3;
    float* ob = out + ((size_t)bh * SLEN + q0 + wave * 16) * DH;
#pragma unroll
    for (int dt = 0; dt < 4; ++dt) {
        int col = ln16 + 16 * dt;
        ob[(quad * 4 + 0) * DH + col] = o[dt][0] * i0;
        ob[(quad * 4 + 1) * DH + col] = o[dt][1] * i1;
        ob[(quad * 4 + 2) * DH + col] = o[dt][2] * i2;
        ob[(quad * 4 + 3) * DH + col] = o[dt][3] * i3;
    }
}

// ---- legacy fallback (round-1 kernel) if ws is too small for the prepass ----
#define LDT 72
__global__ __launch_bounds__(256) void attn_fwd(
    const float* __restrict__ q, const float* __restrict__ kv,
    const float* __restrict__ mask, const int* __restrict__ flags,
    float* __restrict__ out)
{
    __shared__ __align__(16) bf16 Kl[BC * LDT];
    __shared__ __align__(16) bf16 Vt[DH * LDT];
    __shared__ __align__(16) bf16 Pl[BR * LDT];

    const int qt = blockIdx.x;
    const int bh = blockIdx.y;
    const int q0 = qt * BR;
    const int t = threadIdx.x;
    const int wave = t >> 6, lane = t & 63;
    const int ln16 = lane & 15, quad = lane >> 4;

    const float qscale = 0.125f * LOG2E;
    bf16x8 aq[2];
    {
        const float* qrow = q + ((size_t)bh * SLEN + q0 + wave * 16 + ln16) * DH;
#pragma unroll
        for (int kc = 0; kc < 2; ++kc) {
            float4 f0 = *(const float4*)(qrow + kc * 32 + quad * 8);
            float4 f1 = *(const float4*)(qrow + kc * 32 + quad * 8 + 4);
            bf16x8 a;
            a[0] = (bf16)(f0.x * qscale); a[1] = (bf16)(f0.y * qscale);
            a[2] = (bf16)(f0.z * qscale); a[3] = (bf16)(f0.w * qscale);
            a[4] = (bf16)(f1.x * qscale); a[5] = (bf16)(f1.y * qscale);
            a[6] = (bf16)(f1.z * qscale); a[7] = (bf16)(f1.w * qscale);
            aq[kc] = a;
        }
    }

    floatx4 o[4];
#pragma unroll
    for (int dt = 0; dt < 4; ++dt) o[dt] = (floatx4){0.f, 0.f, 0.f, 0.f};
    float m_run[4], l_run[4];
#pragma unroll
    for (int r = 0; r < 4; ++r) { m_run[r] = -3.0e38f; l_run[r] = 0.f; }

    const float* kvb = kv + (size_t)bh * SLEN * DH;

    for (int kt = 0; kt < NKT; ++kt) {
        float4 st[4];
        const float* kvt = kvb + (size_t)kt * BC * DH;
#pragma unroll
        for (int i = 0; i < 4; ++i) {
            int f = i * 256 + t;
            st[i] = *(const float4*)(kvt + (size_t)f * 4);
        }
        __syncthreads();
#pragma unroll
        for (int i = 0; i < 4; ++i) {
            int f = i * 256 + t;
            int key = f >> 4, d4 = (f & 15) * 4;
            bf16 b0 = (bf16)st[i].x, b1 = (bf16)st[i].y, b2 = (bf16)st[i].z, b3 = (bf16)st[i].w;
            *(bf16x4*)&Kl[key * LDT + d4] = (bf16x4){b0, b1, b2, b3};
            Vt[(d4 + 0) * LDT + key] = b0;
            Vt[(d4 + 1) * LDT + key] = b1;
            Vt[(d4 + 2) * LDT + key] = b2;
            Vt[(d4 + 3) * LDT + key] = b3;
        }
        __syncthreads();

        floatx4 s[4];
#pragma unroll
        for (int nt = 0; nt < 4; ++nt) {
            s[nt] = (floatx4){0.f, 0.f, 0.f, 0.f};
#pragma unroll
            for (int kc = 0; kc < 2; ++kc) {
                bf16x8 bk = *(const bf16x8*)&Kl[(ln16 + 16 * nt) * LDT + kc * 32 + quad * 8];
                s[nt] = __builtin_amdgcn_mfma_f32_16x16x32_bf16(aq[kc], bk, s[nt], 0, 0, 0);
            }
        }

        if (!flags || flags[qt * NKT + kt]) {
            const float* mrow = mask + (size_t)(q0 + quad * 4) * SLEN + kt * BC + ln16;
#pragma unroll
            for (int r = 0; r < 4; ++r)
#pragma unroll
                for (int nt = 0; nt < 4; ++nt)
                    s[nt][r] += mrow[(size_t)r * SLEN + nt * 16] * LOG2E;
        }

#pragma unroll
        for (int r = 0; r < 4; ++r) {
            float mx = fmaxf(fmaxf(s[0][r], s[1][r]), fmaxf(s[2][r], s[3][r]));
            mx = fmaxf(mx, __shfl_xor(mx, 1));
            mx = fmaxf(mx, __shfl_xor(mx, 2));
            mx = fmaxf(mx, __shfl_xor(mx, 4));
            mx = fmaxf(mx, __shfl_xor(mx, 8));
            float mnew = fmaxf(m_run[r], mx);
            float alpha = exp2f(m_run[r] - mnew);
            m_run[r] = mnew;
            float rs = 0.f;
#pragma unroll
            for (int nt = 0; nt < 4; ++nt) {
                float p = exp2f(s[nt][r] - mnew);
                s[nt][r] = p;
                rs += p;
            }
            rs += __shfl_xor(rs, 1);
            rs += __shfl_xor(rs, 2);
            rs += __shfl_xor(rs, 4);
            rs += __shfl_xor(rs, 8);
            l_run[r] = l_run[r] * alpha + rs;
#pragma unroll
            for (int dt = 0; dt < 4; ++dt) o[dt][r] *= alpha;
        }

#pragma unroll
        for (int nt = 0; nt < 4; ++nt)
#pragma unroll
            for (int r = 0; r < 4; ++r)
                Pl[(wave * 16 + quad * 4 + r) * LDT + ln16 + 16 * nt] = (bf16)s[nt][r];

#pragma unroll
        for (int kc2 = 0; kc2 < 2; ++kc2) {
            bf16x8 pfr = *(const bf16x8*)&Pl[(wave * 16 + ln16) * LDT + kc2 * 32 + quad * 8];
#pragma unroll
            for (int dt = 0; dt < 4; ++dt) {
                bf16x8 vf = *(const bf16x8*)&Vt[(ln16 + 16 * dt) * LDT + kc2 * 32 + quad * 8];
                o[dt] = __builtin_amdgcn_mfma_f32_16x16x32_bf16(pfr, vf, o[dt], 0, 0, 0);
            }
        }
    }

#pragma unroll
    for (int r = 0; r < 4; ++r) {
        float inv = 1.0f / l_run[r];
        int qrow = q0 + wave * 16 + quad * 4 + r;
        float* orow = out + ((size_t)bh * SLEN + qrow) * DH;
#pragma unroll
        for (int dt = 0; dt < 4; ++dt)
            orow[ln16 + 16 * dt] = o[dt][r] * inv;
    }
}

extern "C" void kernel_launch(void* const* d_in, const int* in_sizes, int n_in,
                              void* d_out, int out_size, void* d_ws, size_t ws_size,
                              hipStream_t stream)
{
    const float* q    = (const float*)d_in[0];
    const float* kv   = (const float*)d_in[1];
    const float* mask = (const float*)d_in[2];
    float* out = (float*)d_out;

    const size_t kvKoff = 4096;                                  // flags: 32*32*4 = 4096
    const size_t kvToff = kvKoff + (size_t)BH_N * SLEN * DH * 2; // 8 MB each
    const size_t need   = kvToff + (size_t)BH_N * SLEN * DH * 2;

    if (ws_size >= need) {
        int*  flags = (int*)d_ws;
        bf16* kvK   = (bf16*)((char*)d_ws + kvKoff);
        bf16* kvT   = (bf16*)((char*)d_ws + kvToff);
        attn_mask_flags<<<dim3(NKT, NQT), 256, 0, stream>>>(mask, flags);
        kv_prep<<<dim3(NKT, BH_N), 256, 0, stream>>>(kv, kvK, kvT);
        attn_fwd2<<<dim3(BH_N, NQT), 256, 0, stream>>>(q, mask, flags, kvK, kvT, out);
    } else {
        int* flags = nullptr;
        if (ws_size >= (size_t)NQT * NKT * sizeof(int)) {
            flags = (int*)d_ws;
            attn_mask_flags<<<dim3(NKT, NQT), 256, 0, stream>>>(mask, flags);
        }
        attn_fwd<<<dim3(NQT, BH_N), 256, 0, stream>>>(q, kv, mask, flags, out);
    }
}

// Round 3
// 172.858 us; speedup vs baseline: 1.4699x; 1.0298x over previous
//
#include <hip/hip_runtime.h>
#include <hip/hip_bf16.h>
#include <stdint.h>

// Flash attention B=4,H=8,S=2048,D=64 fp32 io, bf16 MFMA compute.
// Round 3: prepass bakes LDS-image swizzles (granule rotation + logical key
// permutation) so in-loop ds_read_b128 are conflict-free and PV runs on
// mfma_16x16x32; single-barrier double-buffered global_load_lds pipeline.

typedef __bf16 bf16;
typedef __attribute__((ext_vector_type(8))) __bf16 bf16x8;
typedef __attribute__((ext_vector_type(4))) __bf16 bf16x4;
typedef __attribute__((ext_vector_type(4))) float floatx4;

#define SLEN 2048
#define DH   64
#define BR   64
#define BC   64
#define NKT  (SLEN / BC)
#define NQT  (SLEN / BR)
#define BH_N 32
#define LOG2E 1.44269504088896341f

// LDS image: 8 chunks; chunk = 8 rows x 128B data (1024B) + 64B pad in LDS.
#define CHB_L 1088
#define IMGB_L (8 * CHB_L)     // 8704 B per K or V image in LDS
#define IMGE_G 4096            // bf16 elements per image in global (8192 B)
#define BUFSZ (2 * IMGB_L)     // K + V images per buffer

#define AS1 __attribute__((address_space(1)))
#define AS3 __attribute__((address_space(3)))

static __device__ inline void gload_lds16(const void* g, void* l) {
    __builtin_amdgcn_global_load_lds((const AS1 uint32_t*)g, (AS3 uint32_t*)l, 16, 0, 0);
}

static_assert(BH_N == NQT, "prep kernel folds bh and qt onto one grid axis");

// logical key l (0..63) -> physical key within tile
static __device__ inline int phys_key(int l) {
    int h = l >> 5, l5 = l & 31, q = l5 >> 3, j = l5 & 7;
    return 32 * h + (j < 4 ? 4 * q + j : 16 + 4 * q + (j - 4));
}

// ---- prepass: kv -> swizzled bf16 K/V LDS-images + mask tile flags ----
__global__ __launch_bounds__(256) void kv_prep(
    const float* __restrict__ kv, const float* __restrict__ mask,
    bf16* __restrict__ kvK, bf16* __restrict__ kvT, int* __restrict__ flags)
{
    __shared__ bf16 Tl[64 * 72];
    __shared__ int wany[4];
    const int kt = blockIdx.x, z = blockIdx.y;   // z = bh for kv, z = qt for mask
    const int t = threadIdx.x;

    // mask flag part (z = qt)
    float acc = 0.f;
#pragma unroll
    for (int i = 0; i < 4; ++i) {
        int f = i * 256 + t;
        int row = f >> 4, c4 = (f & 15) * 4;
        const float4 v = *(const float4*)(mask + (size_t)(z * BR + row) * SLEN + kt * BC + c4);
        acc = fmaxf(acc, fmaxf(fmaxf(fabsf(v.x), fabsf(v.y)), fmaxf(fabsf(v.z), fabsf(v.w))));
    }
    unsigned long long any = __ballot(acc != 0.f);
    if ((t & 63) == 0) wany[t >> 6] = (any != 0ull) ? 1 : 0;

    // kv tile load (z = bh): 64 keys x 64 d fp32 -> bf16 Tl[key][d]
    const float* src = kv + ((size_t)z * SLEN + kt * BC) * DH;
#pragma unroll
    for (int i = 0; i < 4; ++i) {
        int f = i * 256 + t;
        int key = f >> 4, d4 = (f & 15) * 4;
        float4 v = *(const float4*)(src + (size_t)key * DH + d4);
        bf16x4 b; b[0] = (bf16)v.x; b[1] = (bf16)v.y; b[2] = (bf16)v.z; b[3] = (bf16)v.w;
        *(bf16x4*)&Tl[key * 72 + d4] = b;
    }
    __syncthreads();
    if (t == 0) flags[z * NKT + kt] = wany[0] | wany[1] | wany[2] | wany[3];

    // K image: granule (c,L): row = 8c+(L>>3) = key, pos p=L&7, content g=(p-row)&7
    bf16* outK = kvK + ((size_t)z * NKT + kt) * IMGE_G;
#pragma unroll
    for (int i = 0; i < 2; ++i) {
        int G = i * 256 + t;
        int c = G >> 6, L = G & 63, rl = L >> 3, p = L & 7;
        int g = (p - rl) & 7, key = 8 * c + rl;
        bf16x8 w = *(const bf16x8*)&Tl[key * 72 + g * 8];
        *(bf16x8*)(outK + (size_t)G * 8) = w;
    }
    // V image: rows = d, content = logical keys 8g..8g+7 gathered via phys_key
    bf16* outV = kvT + ((size_t)z * NKT + kt) * IMGE_G;
#pragma unroll
    for (int i = 0; i < 2; ++i) {
        int G = i * 256 + t;
        int c = G >> 6, L = G & 63, dl = L >> 3, p = L & 7;
        int g = (p - dl) & 7, d = 8 * c + dl;
        bf16x8 w;
#pragma unroll
        for (int j = 0; j < 8; ++j)
            w[j] = Tl[phys_key(8 * g + j) * 72 + d];
        *(bf16x8*)(outV + (size_t)G * 8) = w;
    }
}

// ---- main fused attention ----
__global__ __launch_bounds__(256) void attn_fwd3(
    const float* __restrict__ q, const float* __restrict__ mask,
    const int* __restrict__ flags,
    const bf16* __restrict__ kvK, const bf16* __restrict__ kvT,
    float* __restrict__ out)
{
    __shared__ __align__(16) char smem[2 * BUFSZ];

    const int bh = blockIdx.x;
    const int qt = blockIdx.y;
    const int q0 = qt * BR;
    const int t = threadIdx.x;
    const int wave = t >> 6, lane = t & 63;
    const int ln16 = lane & 15, quad = lane >> 4;
    const int ln8 = ln16 & 7, hb = ln16 >> 3;

    // Q B-fragments (scale folded): B[k=kc*32+quad*8+j][n=qrow=ln16]
    const float qscale = 0.125f * LOG2E;
    bf16x8 aq[2];
    {
        const float* qrow = q + ((size_t)bh * SLEN + q0 + wave * 16 + ln16) * DH;
#pragma unroll
        for (int kc = 0; kc < 2; ++kc) {
            float4 f0 = *(const float4*)(qrow + kc * 32 + quad * 8);
            float4 f1 = *(const float4*)(qrow + kc * 32 + quad * 8 + 4);
            bf16x8 a;
            a[0] = (bf16)(f0.x * qscale); a[1] = (bf16)(f0.y * qscale);
            a[2] = (bf16)(f0.z * qscale); a[3] = (bf16)(f0.w * qscale);
            a[4] = (bf16)(f1.x * qscale); a[5] = (bf16)(f1.y * qscale);
            a[6] = (bf16)(f1.z * qscale); a[7] = (bf16)(f1.w * qscale);
            aq[kc] = a;
        }
    }

    // flag bitmask for this qt (bit kt)
    unsigned fmask;
    {
        int ld = (lane < 32) ? flags[qt * NKT + lane] : 0;
        fmask = (unsigned)__ballot(ld != 0);
    }

    // conflict-free swizzled read offsets (same for K and V images)
    const int kbase0 = hb * CHB_L + ln8 * 128 + (((quad + ln8) & 7) << 4);
    const int kbase1 = hb * CHB_L + ln8 * 128 + (((quad + 4 + ln8) & 7) << 4);

    floatx4 o[4];
#pragma unroll
    for (int dt = 0; dt < 4; ++dt) o[dt] = (floatx4){0.f, 0.f, 0.f, 0.f};
    float m_run = -3.0e38f, l_run = 0.f;

    const bf16* kvKb = kvK + (size_t)bh * NKT * IMGE_G;
    const bf16* kvTb = kvT + (size_t)bh * NKT * IMGE_G;

    // prologue: stage tile 0 into buffer 0
    {
        char* Kd = smem;
        char* Vd = smem + IMGB_L;
#pragma unroll
        for (int j = 0; j < 2; ++j) {
            int ch = wave * 2 + j;
            gload_lds16(kvKb + (size_t)ch * 512 + lane * 8, Kd + ch * CHB_L);
            gload_lds16(kvTb + (size_t)ch * 512 + lane * 8, Vd + ch * CHB_L);
        }
    }

    for (int kt = 0; kt < NKT; ++kt) {
        __syncthreads();   // drains vmcnt -> buf[kt&1] ready; prev compute done

        if (kt + 1 < NKT) {   // prefetch next tile into the other buffer
            char* Kd = smem + ((kt + 1) & 1) * BUFSZ;
            char* Vd = Kd + IMGB_L;
            const bf16* gK = kvKb + (size_t)(kt + 1) * IMGE_G;
            const bf16* gV = kvTb + (size_t)(kt + 1) * IMGE_G;
#pragma unroll
            for (int j = 0; j < 2; ++j) {
                int ch = wave * 2 + j;
                gload_lds16(gK + (size_t)ch * 512 + lane * 8, Kd + ch * CHB_L);
                gload_lds16(gV + (size_t)ch * 512 + lane * 8, Vd + ch * CHB_L);
            }
        }

        const char* Kb = smem + (kt & 1) * BUFSZ;
        const char* Vb = Kb + IMGB_L;

        // S^T = K * Q^T : D[m=phys key][n=qrow]
        floatx4 s[4];
#pragma unroll
        for (int nt = 0; nt < 4; ++nt) {
            bf16x8 k0 = *(const bf16x8*)(Kb + nt * 2176 + kbase0);
            bf16x8 k1 = *(const bf16x8*)(Kb + nt * 2176 + kbase1);
            floatx4 acc = (floatx4){0.f, 0.f, 0.f, 0.f};
            acc = __builtin_amdgcn_mfma_f32_16x16x32_bf16(k0, aq[0], acc, 0, 0, 0);
            acc = __builtin_amdgcn_mfma_f32_16x16x32_bf16(k1, aq[1], acc, 0, 0, 0);
            s[nt] = acc;
        }

        // mask add (phys key = 16nt+quad*4+r, qrow = ln16); usually skipped
        if (fmask & (1u << kt)) {
            const float* mrow = mask + (size_t)(q0 + wave * 16 + ln16) * SLEN + kt * BC;
#pragma unroll
            for (int nt = 0; nt < 4; ++nt) {
                float4 mv = *(const float4*)(mrow + 16 * nt + quad * 4);
                s[nt][0] += mv.x * LOG2E; s[nt][1] += mv.y * LOG2E;
                s[nt][2] += mv.z * LOG2E; s[nt][3] += mv.w * LOG2E;
            }
        }

        // online softmax: one q-row per lane (row = ln16)
        float t01 = fmaxf(fmaxf(s[0][0], s[0][1]), fmaxf(s[0][2], s[0][3]));
        float t23 = fmaxf(fmaxf(s[1][0], s[1][1]), fmaxf(s[1][2], s[1][3]));
        float t45 = fmaxf(fmaxf(s[2][0], s[2][1]), fmaxf(s[2][2], s[2][3]));
        float t67 = fmaxf(fmaxf(s[3][0], s[3][1]), fmaxf(s[3][2], s[3][3]));
        float tmax = fmaxf(fmaxf(t01, t23), fmaxf(t45, t67));
        tmax = fmaxf(tmax, __shfl_xor(tmax, 16));
        tmax = fmaxf(tmax, __shfl_xor(tmax, 32));
        float mnew = fmaxf(m_run, tmax);
        unsigned long long grew = __ballot(mnew > m_run);
        float alpha = exp2f(m_run - mnew);
        m_run = mnew;

        float rs = 0.f;
        bf16x8 pf0, pf1;
#pragma unroll
        for (int r = 0; r < 4; ++r) {
            float p0 = exp2f(s[0][r] - mnew);
            float p1 = exp2f(s[1][r] - mnew);
            float p2 = exp2f(s[2][r] - mnew);
            float p3 = exp2f(s[3][r] - mnew);
            rs += (p0 + p1) + (p2 + p3);
            pf0[r] = (bf16)p0; pf0[4 + r] = (bf16)p1;
            pf1[r] = (bf16)p2; pf1[4 + r] = (bf16)p3;
        }
        rs += __shfl_xor(rs, 16);
        rs += __shfl_xor(rs, 32);

        if (grew) {
            l_run = l_run * alpha + rs;
            float a0 = __shfl(alpha, quad * 4 + 0);
            float a1 = __shfl(alpha, quad * 4 + 1);
            float a2 = __shfl(alpha, quad * 4 + 2);
            float a3 = __shfl(alpha, quad * 4 + 3);
#pragma unroll
            for (int dt = 0; dt < 4; ++dt) {
                o[dt][0] *= a0; o[dt][1] *= a1; o[dt][2] *= a2; o[dt][3] *= a3;
            }
        } else {
            l_run += rs;
        }

        // O += P V : A = pf (logical key order), B = V image rows d
#pragma unroll
        for (int dt = 0; dt < 4; ++dt) {
            bf16x8 v0 = *(const bf16x8*)(Vb + dt * 2176 + kbase0);
            bf16x8 v1 = *(const bf16x8*)(Vb + dt * 2176 + kbase1);
            o[dt] = __builtin_amdgcn_mfma_f32_16x16x32_bf16(pf0, v0, o[dt], 0, 0, 0);
            o[dt] = __builtin_amdgcn_mfma_f32_16x16x32_bf16(pf1, v1, o[dt], 0, 0, 0);
        }
    }

    // epilogue: O rows = quad*4+r, cols = ln16+16dt; l lives at lane quad*4+r
    float l0 = __shfl(l_run, quad * 4 + 0);
    float l1 = __shfl(l_run, quad * 4 + 1);
    float l2 = __shfl(l_run, quad * 4 + 2);
    float l3 = __shfl(l_run, quad * 4 + 3);
    float i0 = 1.f / l0, i1 = 1.f / l1, i2 = 1.f / l2, i3 = 1.f / l3;
    float* ob = out + ((size_t)bh * SLEN + q0 + wave * 16) * DH;
#pragma unroll
    for (int dt = 0; dt < 4; ++dt) {
        int col = ln16 + 16 * dt;
        ob[(quad * 4 + 0) * DH + col] = o[dt][0] * i0;
        ob[(quad * 4 + 1) * DH + col] = o[dt][1] * i1;
        ob[(quad * 4 + 2) * DH + col] = o[dt][2] * i2;
        ob[(quad * 4 + 3) * DH + col] = o[dt][3] * i3;
    }
}

// ---- legacy fallback (round-1 kernel) if ws is too small for the prepass ----
#define LDT 72
__global__ __launch_bounds__(256) void attn_mask_flags(
    const float* __restrict__ mask, int* __restrict__ flags)
{
    const int kt = blockIdx.x, qt = blockIdx.y;
    const int t = threadIdx.x;
    float acc = 0.f;
#pragma unroll
    for (int i = 0; i < 4; ++i) {
        int f = i * 256 + t;
        int row = f >> 4, c4 = (f & 15) * 4;
        const float4 v = *(const float4*)(mask + (size_t)(qt * BR + row) * SLEN + kt * BC + c4);
        acc = fmaxf(acc, fmaxf(fmaxf(fabsf(v.x), fabsf(v.y)), fmaxf(fabsf(v.z), fabsf(v.w))));
    }
    unsigned long long any = __ballot(acc != 0.f);
    __shared__ int wany[4];
    if ((t & 63) == 0) wany[t >> 6] = (any != 0ull) ? 1 : 0;
    __syncthreads();
    if (t == 0) flags[qt * NKT + kt] = wany[0] | wany[1] | wany[2] | wany[3];
}

__global__ __launch_bounds__(256) void attn_fwd(
    const float* __restrict__ q, const float* __restrict__ kv,
    const float* __restrict__ mask, const int* __restrict__ flags,
    float* __restrict__ out)
{
    __shared__ __align__(16) bf16 Kl[BC * LDT];
    __shared__ __align__(16) bf16 Vt[DH * LDT];
    __shared__ __align__(16) bf16 Pl[BR * LDT];

    const int qt = blockIdx.x;
    const int bh = blockIdx.y;
    const int q0 = qt * BR;
    const int t = threadIdx.x;
    const int wave = t >> 6, lane = t & 63;
    const int ln16 = lane & 15, quad = lane >> 4;

    const float qscale = 0.125f * LOG2E;
    bf16x8 aq[2];
    {
        const float* qrow = q + ((size_t)bh * SLEN + q0 + wave * 16 + ln16) * DH;
#pragma unroll
        for (int kc = 0; kc < 2; ++kc) {
            float4 f0 = *(const float4*)(qrow + kc * 32 + quad * 8);
            float4 f1 = *(const float4*)(qrow + kc * 32 + quad * 8 + 4);
            bf16x8 a;
            a[0] = (bf16)(f0.x * qscale); a[1] = (bf16)(f0.y * qscale);
            a[2] = (bf16)(f0.z * qscale); a[3] = (bf16)(f0.w * qscale);
            a[4] = (bf16)(f1.x * qscale); a[5] = (bf16)(f1.y * qscale);
            a[6] = (bf16)(f1.z * qscale); a[7] = (bf16)(f1.w * qscale);
            aq[kc] = a;
        }
    }

    floatx4 o[4];
#pragma unroll
    for (int dt = 0; dt < 4; ++dt) o[dt] = (floatx4){0.f, 0.f, 0.f, 0.f};
    float m_run[4], l_run[4];
#pragma unroll
    for (int r = 0; r < 4; ++r) { m_run[r] = -3.0e38f; l_run[r] = 0.f; }

    const float* kvb = kv + (size_t)bh * SLEN * DH;

    for (int kt = 0; kt < NKT; ++kt) {
        float4 st[4];
        const float* kvt = kvb + (size_t)kt * BC * DH;
#pragma unroll
        for (int i = 0; i < 4; ++i) {
            int f = i * 256 + t;
            st[i] = *(const float4*)(kvt + (size_t)f * 4);
        }
        __syncthreads();
#pragma unroll
        for (int i = 0; i < 4; ++i) {
            int f = i * 256 + t;
            int key = f >> 4, d4 = (f & 15) * 4;
            bf16 b0 = (bf16)st[i].x, b1 = (bf16)st[i].y, b2 = (bf16)st[i].z, b3 = (bf16)st[i].w;
            *(bf16x4*)&Kl[key * LDT + d4] = (bf16x4){b0, b1, b2, b3};
            Vt[(d4 + 0) * LDT + key] = b0;
            Vt[(d4 + 1) * LDT + key] = b1;
            Vt[(d4 + 2) * LDT + key] = b2;
            Vt[(d4 + 3) * LDT + key] = b3;
        }
        __syncthreads();

        floatx4 s[4];
#pragma unroll
        for (int nt = 0; nt < 4; ++nt) {
            s[nt] = (floatx4){0.f, 0.f, 0.f, 0.f};
#pragma unroll
            for (int kc = 0; kc < 2; ++kc) {
                bf16x8 bk = *(const bf16x8*)&Kl[(ln16 + 16 * nt) * LDT + kc * 32 + quad * 8];
                s[nt] = __builtin_amdgcn_mfma_f32_16x16x32_bf16(aq[kc], bk, s[nt], 0, 0, 0);
            }
        }

        if (!flags || flags[qt * NKT + kt]) {
            const float* mrow = mask + (size_t)(q0 + quad * 4) * SLEN + kt * BC + ln16;
#pragma unroll
            for (int r = 0; r < 4; ++r)
#pragma unroll
                for (int nt = 0; nt < 4; ++nt)
                    s[nt][r] += mrow[(size_t)r * SLEN + nt * 16] * LOG2E;
        }

#pragma unroll
        for (int r = 0; r < 4; ++r) {
            float mx = fmaxf(fmaxf(s[0][r], s[1][r]), fmaxf(s[2][r], s[3][r]));
            mx = fmaxf(mx, __shfl_xor(mx, 1));
            mx = fmaxf(mx, __shfl_xor(mx, 2));
            mx = fmaxf(mx, __shfl_xor(mx, 4));
            mx = fmaxf(mx, __shfl_xor(mx, 8));
            float mnew = fmaxf(m_run[r], mx);
            float alpha = exp2f(m_run[r] - mnew);
            m_run[r] = mnew;
            float rs = 0.f;
#pragma unroll
            for (int nt = 0; nt < 4; ++nt) {
                float p = exp2f(s[nt][r] - mnew);
                s[nt][r] = p;
                rs += p;
            }
            rs += __shfl_xor(rs, 1);
            rs += __shfl_xor(rs, 2);
            rs += __shfl_xor(rs, 4);
            rs += __shfl_xor(rs, 8);
            l_run[r] = l_run[r] * alpha + rs;
#pragma unroll
            for (int dt = 0; dt < 4; ++dt) o[dt][r] *= alpha;
        }

#pragma unroll
        for (int nt = 0; nt < 4; ++nt)
#pragma unroll
            for (int r = 0; r < 4; ++r)
                Pl[(wave * 16 + quad * 4 + r) * LDT + ln16 + 16 * nt] = (bf16)s[nt][r];

#pragma unroll
        for (int kc2 = 0; kc2 < 2; ++kc2) {
            bf16x8 pfr = *(const bf16x8*)&Pl[(wave * 16 + ln16) * LDT + kc2 * 32 + quad * 8];
#pragma unroll
            for (int dt = 0; dt < 4; ++dt) {
                bf16x8 vf = *(const bf16x8*)&Vt[(ln16 + 16 * dt) * LDT + kc2 * 32 + quad * 8];
                o[dt] = __builtin_amdgcn_mfma_f32_16x16x32_bf16(pfr, vf, o[dt], 0, 0, 0);
            }
        }
    }

#pragma unroll
    for (int r = 0; r < 4; ++r) {
        float inv = 1.0f / l_run[r];
        int qrow = q0 + wave * 16 + quad * 4 + r;
        float* orow = out + ((size_t)bh * SLEN + qrow) * DH;
#pragma unroll
        for (int dt = 0; dt < 4; ++dt)
            orow[ln16 + 16 * dt] = o[dt][r] * inv;
    }
}

extern "C" void kernel_launch(void* const* d_in, const int* in_sizes, int n_in,
                              void* d_out, int out_size, void* d_ws, size_t ws_size,
                              hipStream_t stream)
{
    const float* q    = (const float*)d_in[0];
    const float* kv   = (const float*)d_in[1];
    const float* mask = (const float*)d_in[2];
    float* out = (float*)d_out;

    const size_t kvKoff = 4096;                                   // flags: 32*32*4
    const size_t kvToff = kvKoff + (size_t)BH_N * NKT * IMGE_G * 2;
    const size_t need   = kvToff + (size_t)BH_N * NKT * IMGE_G * 2;

    if (ws_size >= need) {
        int*  flags = (int*)d_ws;
        bf16* kvK   = (bf16*)((char*)d_ws + kvKoff);
        bf16* kvT   = (bf16*)((char*)d_ws + kvToff);
        kv_prep<<<dim3(NKT, BH_N), 256, 0, stream>>>(kv, mask, kvK, kvT, flags);
        attn_fwd3<<<dim3(BH_N, NQT), 256, 0, stream>>>(q, mask, flags, kvK, kvT, out);
    } else {
        int* flags = nullptr;
        if (ws_size >= (size_t)NQT * NKT * sizeof(int)) {
            flags = (int*)d_ws;
            attn_mask_flags<<<dim3(NKT, NQT), 256, 0, stream>>>(mask, flags);
        }
        attn_fwd<<<dim3(NQT, BH_N), 256, 0, stream>>>(q, kv, mask, flags, out);
    }
}

// Round 6
// 159.657 us; speedup vs baseline: 1.5914x; 1.0827x over previous
//
#include <hip/hip_runtime.h>
#include <hip/hip_bf16.h>
#include <stdint.h>

// Flash attention B=4,H=8,S=2048,D=64 fp32 io, bf16 MFMA compute.
// Round 6: EXACT R3-verified numerics (online softmax) and pipeline; only
// change is 8 waves/block (512 thr, 128 q-rows/block) -> 16 waves/CU and
// half the staging/barrier cost per q-row.

typedef __bf16 bf16;
typedef __attribute__((ext_vector_type(8))) __bf16 bf16x8;
typedef __attribute__((ext_vector_type(4))) __bf16 bf16x4;
typedef __attribute__((ext_vector_type(4))) float floatx4;

#define SLEN 2048
#define DH   64
#define BR   64
#define BC   64
#define NKT  (SLEN / BC)
#define NQT  (SLEN / BR)
#define BH_N 32
#define LOG2E 1.44269504088896341f

// LDS image: 8 chunks; chunk = 8 rows x 128B data (1024B) + 64B pad in LDS.
#define CHB_L 1088
#define IMGB_L (8 * CHB_L)     // 8704 B per K or V image in LDS
#define IMGE_G 4096            // bf16 elements per image in global (8192 B)
#define BUFSZ (2 * IMGB_L)     // K + V images per buffer

#define AS1 __attribute__((address_space(1)))
#define AS3 __attribute__((address_space(3)))

static __device__ inline void gload_lds16(const void* g, void* l) {
    __builtin_amdgcn_global_load_lds((const AS1 uint32_t*)g, (AS3 uint32_t*)l, 16, 0, 0);
}

static_assert(BH_N == NQT, "prep kernel folds bh and qt onto one grid axis");

// logical key l (0..63) -> physical key within tile
static __device__ inline int phys_key(int l) {
    int h = l >> 5, l5 = l & 31, q = l5 >> 3, j = l5 & 7;
    return 32 * h + (j < 4 ? 4 * q + j : 16 + 4 * q + (j - 4));
}

// ---- prepass: kv -> swizzled bf16 K/V LDS-images + mask tile flags ----
__global__ __launch_bounds__(256) void kv_prep(
    const float* __restrict__ kv, const float* __restrict__ mask,
    bf16* __restrict__ kvK, bf16* __restrict__ kvT, int* __restrict__ flags)
{
    __shared__ bf16 Tl[64 * 72];
    __shared__ int wany[4];
    const int kt = blockIdx.x, z = blockIdx.y;   // z = bh for kv, z = qt for mask
    const int t = threadIdx.x;

    // mask flag part (z = qt)
    float acc = 0.f;
#pragma unroll
    for (int i = 0; i < 4; ++i) {
        int f = i * 256 + t;
        int row = f >> 4, c4 = (f & 15) * 4;
        const float4 v = *(const float4*)(mask + (size_t)(z * BR + row) * SLEN + kt * BC + c4);
        acc = fmaxf(acc, fmaxf(fmaxf(fabsf(v.x), fabsf(v.y)), fmaxf(fabsf(v.z), fabsf(v.w))));
    }
    unsigned long long any = __ballot(acc != 0.f);
    if ((t & 63) == 0) wany[t >> 6] = (any != 0ull) ? 1 : 0;

    // kv tile load (z = bh): 64 keys x 64 d fp32 -> bf16 Tl[key][d]
    const float* src = kv + ((size_t)z * SLEN + kt * BC) * DH;
#pragma unroll
    for (int i = 0; i < 4; ++i) {
        int f = i * 256 + t;
        int key = f >> 4, d4 = (f & 15) * 4;
        float4 v = *(const float4*)(src + (size_t)key * DH + d4);
        bf16x4 b; b[0] = (bf16)v.x; b[1] = (bf16)v.y; b[2] = (bf16)v.z; b[3] = (bf16)v.w;
        *(bf16x4*)&Tl[key * 72 + d4] = b;
    }
    __syncthreads();
    if (t == 0) flags[z * NKT + kt] = wany[0] | wany[1] | wany[2] | wany[3];

    // K image: granule (c,L): row = 8c+(L>>3) = key, pos p=L&7, content g=(p-row)&7
    bf16* outK = kvK + ((size_t)z * NKT + kt) * IMGE_G;
#pragma unroll
    for (int i = 0; i < 2; ++i) {
        int G = i * 256 + t;
        int c = G >> 6, L = G & 63, rl = L >> 3, p = L & 7;
        int g = (p - rl) & 7, key = 8 * c + rl;
        bf16x8 w = *(const bf16x8*)&Tl[key * 72 + g * 8];
        *(bf16x8*)(outK + (size_t)G * 8) = w;
    }
    // V image: rows = d, content = logical keys 8g..8g+7 gathered via phys_key
    bf16* outV = kvT + ((size_t)z * NKT + kt) * IMGE_G;
#pragma unroll
    for (int i = 0; i < 2; ++i) {
        int G = i * 256 + t;
        int c = G >> 6, L = G & 63, dl = L >> 3, p = L & 7;
        int g = (p - dl) & 7, d = 8 * c + dl;
        bf16x8 w;
#pragma unroll
        for (int j = 0; j < 8; ++j)
            w[j] = Tl[phys_key(8 * g + j) * 72 + d];
        *(bf16x8*)(outV + (size_t)G * 8) = w;
    }
}

// ---- main fused attention: R3 numerics, 8 waves / 128 q-rows per block ----
__global__ __launch_bounds__(512) void attn_fwd6(
    const float* __restrict__ q, const float* __restrict__ mask,
    const int* __restrict__ flags,
    const bf16* __restrict__ kvK, const bf16* __restrict__ kvT,
    float* __restrict__ out)
{
    __shared__ __align__(16) char smem[2 * BUFSZ];

    const int bh = blockIdx.x;
    const int qt = blockIdx.y;          // 128-row q tile
    const int q0 = qt * 128;
    const int t = threadIdx.x;
    const int wave = t >> 6, lane = t & 63;   // wave in [0,8)
    const int ln16 = lane & 15, quad = lane >> 4;
    const int ln8 = ln16 & 7, hb = ln16 >> 3;

    // Q B-fragments (scale folded): B[k=kc*32+quad*8+j][n=qrow=ln16]
    const float qscale = 0.125f * LOG2E;
    bf16x8 aq[2];
    {
        const float* qrow = q + ((size_t)bh * SLEN + q0 + wave * 16 + ln16) * DH;
#pragma unroll
        for (int kc = 0; kc < 2; ++kc) {
            float4 f0 = *(const float4*)(qrow + kc * 32 + quad * 8);
            float4 f1 = *(const float4*)(qrow + kc * 32 + quad * 8 + 4);
            bf16x8 a;
            a[0] = (bf16)(f0.x * qscale); a[1] = (bf16)(f0.y * qscale);
            a[2] = (bf16)(f0.z * qscale); a[3] = (bf16)(f0.w * qscale);
            a[4] = (bf16)(f1.x * qscale); a[5] = (bf16)(f1.y * qscale);
            a[6] = (bf16)(f1.z * qscale); a[7] = (bf16)(f1.w * qscale);
            aq[kc] = a;
        }
    }

    // flag bitmask for this wave's 64-row flag tile (bit kt)
    const int fqt = qt * 2 + (wave >> 2);
    unsigned fmask;
    {
        int ld = (lane < 32) ? flags[fqt * NKT + lane] : 0;
        fmask = (unsigned)__ballot(ld != 0);
    }

    // conflict-swizzled read offsets (same for K and V images)
    const int kbase0 = hb * CHB_L + ln8 * 128 + (((quad + ln8) & 7) << 4);
    const int kbase1 = hb * CHB_L + ln8 * 128 + (((quad + 4 + ln8) & 7) << 4);

    floatx4 o[4];
#pragma unroll
    for (int dt = 0; dt < 4; ++dt) o[dt] = (floatx4){0.f, 0.f, 0.f, 0.f};
    float m_run = -3.0e38f, l_run = 0.f;

    const bf16* kvKb = kvK + (size_t)bh * NKT * IMGE_G;
    const bf16* kvTb = kvT + (size_t)bh * NKT * IMGE_G;

    // prologue: stage tile 0 into buffer 0 (each wave: 1 chunk per image)
    {
        char* Kd = smem;
        char* Vd = smem + IMGB_L;
        gload_lds16(kvKb + (size_t)wave * 512 + lane * 8, Kd + wave * CHB_L);
        gload_lds16(kvTb + (size_t)wave * 512 + lane * 8, Vd + wave * CHB_L);
    }

    for (int kt = 0; kt < NKT; ++kt) {
        __syncthreads();   // drains vmcnt -> buf[kt&1] ready; prev compute done

        if (kt + 1 < NKT) {   // prefetch next tile into the other buffer
            char* Kd = smem + ((kt + 1) & 1) * BUFSZ;
            char* Vd = Kd + IMGB_L;
            const bf16* gK = kvKb + (size_t)(kt + 1) * IMGE_G;
            const bf16* gV = kvTb + (size_t)(kt + 1) * IMGE_G;
            gload_lds16(gK + (size_t)wave * 512 + lane * 8, Kd + wave * CHB_L);
            gload_lds16(gV + (size_t)wave * 512 + lane * 8, Vd + wave * CHB_L);
        }

        const char* Kb = smem + (kt & 1) * BUFSZ;
        const char* Vb = Kb + IMGB_L;

        // S^T = K * Q^T : D[m=phys key][n=qrow]
        floatx4 s[4];
#pragma unroll
        for (int nt = 0; nt < 4; ++nt) {
            bf16x8 k0 = *(const bf16x8*)(Kb + nt * 2176 + kbase0);
            bf16x8 k1 = *(const bf16x8*)(Kb + nt * 2176 + kbase1);
            floatx4 acc = (floatx4){0.f, 0.f, 0.f, 0.f};
            acc = __builtin_amdgcn_mfma_f32_16x16x32_bf16(k0, aq[0], acc, 0, 0, 0);
            acc = __builtin_amdgcn_mfma_f32_16x16x32_bf16(k1, aq[1], acc, 0, 0, 0);
            s[nt] = acc;
        }

        // mask add (phys key = 16nt+quad*4+r, qrow = ln16); usually skipped
        if (fmask & (1u << kt)) {
            const float* mrow = mask + (size_t)(q0 + wave * 16 + ln16) * SLEN + kt * BC;
#pragma unroll
            for (int nt = 0; nt < 4; ++nt) {
                float4 mv = *(const float4*)(mrow + 16 * nt + quad * 4);
                s[nt][0] += mv.x * LOG2E; s[nt][1] += mv.y * LOG2E;
                s[nt][2] += mv.z * LOG2E; s[nt][3] += mv.w * LOG2E;
            }
        }

        // online softmax: one q-row per lane (row = ln16)
        float t01 = fmaxf(fmaxf(s[0][0], s[0][1]), fmaxf(s[0][2], s[0][3]));
        float t23 = fmaxf(fmaxf(s[1][0], s[1][1]), fmaxf(s[1][2], s[1][3]));
        float t45 = fmaxf(fmaxf(s[2][0], s[2][1]), fmaxf(s[2][2], s[2][3]));
        float t67 = fmaxf(fmaxf(s[3][0], s[3][1]), fmaxf(s[3][2], s[3][3]));
        float tmax = fmaxf(fmaxf(t01, t23), fmaxf(t45, t67));
        tmax = fmaxf(tmax, __shfl_xor(tmax, 16));
        tmax = fmaxf(tmax, __shfl_xor(tmax, 32));
        float mnew = fmaxf(m_run, tmax);
        unsigned long long grew = __ballot(mnew > m_run);
        float alpha = exp2f(m_run - mnew);
        m_run = mnew;

        float rs = 0.f;
        bf16x8 pf0, pf1;
#pragma unroll
        for (int r = 0; r < 4; ++r) {
            float p0 = exp2f(s[0][r] - mnew);
            float p1 = exp2f(s[1][r] - mnew);
            float p2 = exp2f(s[2][r] - mnew);
            float p3 = exp2f(s[3][r] - mnew);
            rs += (p0 + p1) + (p2 + p3);
            pf0[r] = (bf16)p0; pf0[4 + r] = (bf16)p1;
            pf1[r] = (bf16)p2; pf1[4 + r] = (bf16)p3;
        }
        rs += __shfl_xor(rs, 16);
        rs += __shfl_xor(rs, 32);

        if (grew) {
            l_run = l_run * alpha + rs;
            float a0 = __shfl(alpha, quad * 4 + 0);
            float a1 = __shfl(alpha, quad * 4 + 1);
            float a2 = __shfl(alpha, quad * 4 + 2);
            float a3 = __shfl(alpha, quad * 4 + 3);
#pragma unroll
            for (int dt = 0; dt < 4; ++dt) {
                o[dt][0] *= a0; o[dt][1] *= a1; o[dt][2] *= a2; o[dt][3] *= a3;
            }
        } else {
            l_run += rs;
        }

        // O += P V : A = pf (logical key order), B = V image rows d
#pragma unroll
        for (int dt = 0; dt < 4; ++dt) {
            bf16x8 v0 = *(const bf16x8*)(Vb + dt * 2176 + kbase0);
            bf16x8 v1 = *(const bf16x8*)(Vb + dt * 2176 + kbase1);
            o[dt] = __builtin_amdgcn_mfma_f32_16x16x32_bf16(pf0, v0, o[dt], 0, 0, 0);
            o[dt] = __builtin_amdgcn_mfma_f32_16x16x32_bf16(pf1, v1, o[dt], 0, 0, 0);
        }
    }

    // epilogue: O rows = quad*4+r, cols = ln16+16dt; l lives at lane quad*4+r
    float l0 = __shfl(l_run, quad * 4 + 0);
    float l1 = __shfl(l_run, quad * 4 + 1);
    float l2 = __shfl(l_run, quad * 4 + 2);
    float l3 = __shfl(l_run, quad * 4 + 3);
    float i0 = 1.f / l0, i1 = 1.f / l1, i2 = 1.f / l2, i3 = 1.f / l3;
    float* ob = out + ((size_t)bh * SLEN + q0 + wave * 16) * DH;
#pragma unroll
    for (int dt = 0; dt < 4; ++dt) {
        int col = ln16 + 16 * dt;
        ob[(quad * 4 + 0) * DH + col] = o[dt][0] * i0;
        ob[(quad * 4 + 1) * DH + col] = o[dt][1] * i1;
        ob[(quad * 4 + 2) * DH + col] = o[dt][2] * i2;
        ob[(quad * 4 + 3) * DH + col] = o[dt][3] * i3;
    }
}

// ---- legacy fallback (round-1 kernel) if ws is too small for the prepass ----
#define LDT 72
__global__ __launch_bounds__(256) void attn_mask_flags(
    const float* __restrict__ mask, int* __restrict__ flags)
{
    const int kt = blockIdx.x, qt = blockIdx.y;
    const int t = threadIdx.x;
    float acc = 0.f;
#pragma unroll
    for (int i = 0; i < 4; ++i) {
        int f = i * 256 + t;
        int row = f >> 4, c4 = (f & 15) * 4;
        const float4 v = *(const float4*)(mask + (size_t)(qt * BR + row) * SLEN + kt * BC + c4);
        acc = fmaxf(acc, fmaxf(fmaxf(fabsf(v.x), fabsf(v.y)), fmaxf(fabsf(v.z), fabsf(v.w))));
    }
    unsigned long long any = __ballot(acc != 0.f);
    __shared__ int wany[4];
    if ((t & 63) == 0) wany[t >> 6] = (any != 0ull) ? 1 : 0;
    __syncthreads();
    if (t == 0) flags[qt * NKT + kt] = wany[0] | wany[1] | wany[2] | wany[3];
}

__global__ __launch_bounds__(256) void attn_fwd(
    const float* __restrict__ q, const float* __restrict__ kv,
    const float* __restrict__ mask, const int* __restrict__ flags,
    float* __restrict__ out)
{
    __shared__ __align__(16) bf16 Kl[BC * LDT];
    __shared__ __align__(16) bf16 Vt[DH * LDT];
    __shared__ __align__(16) bf16 Pl[BR * LDT];

    const int qt = blockIdx.x;
    const int bh = blockIdx.y;
    const int q0 = qt * BR;
    const int t = threadIdx.x;
    const int wave = t >> 6, lane = t & 63;
    const int ln16 = lane & 15, quad = lane >> 4;

    const float qscale = 0.125f * LOG2E;
    bf16x8 aq[2];
    {
        const float* qrow = q + ((size_t)bh * SLEN + q0 + wave * 16 + ln16) * DH;
#pragma unroll
        for (int kc = 0; kc < 2; ++kc) {
            float4 f0 = *(const float4*)(qrow + kc * 32 + quad * 8);
            float4 f1 = *(const float4*)(qrow + kc * 32 + quad * 8 + 4);
            bf16x8 a;
            a[0] = (bf16)(f0.x * qscale); a[1] = (bf16)(f0.y * qscale);
            a[2] = (bf16)(f0.z * qscale); a[3] = (bf16)(f0.w * qscale);
            a[4] = (bf16)(f1.x * qscale); a[5] = (bf16)(f1.y * qscale);
            a[6] = (bf16)(f1.z * qscale); a[7] = (bf16)(f1.w * qscale);
            aq[kc] = a;
        }
    }

    floatx4 o[4];
#pragma unroll
    for (int dt = 0; dt < 4; ++dt) o[dt] = (floatx4){0.f, 0.f, 0.f, 0.f};
    float m_run[4], l_run[4];
#pragma unroll
    for (int r = 0; r < 4; ++r) { m_run[r] = -3.0e38f; l_run[r] = 0.f; }

    const float* kvb = kv + (size_t)bh * SLEN * DH;

    for (int kt = 0; kt < NKT; ++kt) {
        float4 st[4];
        const float* kvt = kvb + (size_t)kt * BC * DH;
#pragma unroll
        for (int i = 0; i < 4; ++i) {
            int f = i * 256 + t;
            st[i] = *(const float4*)(kvt + (size_t)f * 4);
        }
        __syncthreads();
#pragma unroll
        for (int i = 0; i < 4; ++i) {
            int f = i * 256 + t;
            int key = f >> 4, d4 = (f & 15) * 4;
            bf16 b0 = (bf16)st[i].x, b1 = (bf16)st[i].y, b2 = (bf16)st[i].z, b3 = (bf16)st[i].w;
            *(bf16x4*)&Kl[key * LDT + d4] = (bf16x4){b0, b1, b2, b3};
            Vt[(d4 + 0) * LDT + key] = b0;
            Vt[(d4 + 1) * LDT + key] = b1;
            Vt[(d4 + 2) * LDT + key] = b2;
            Vt[(d4 + 3) * LDT + key] = b3;
        }
        __syncthreads();

        floatx4 s[4];
#pragma unroll
        for (int nt = 0; nt < 4; ++nt) {
            s[nt] = (floatx4){0.f, 0.f, 0.f, 0.f};
#pragma unroll
            for (int kc = 0; kc < 2; ++kc) {
                bf16x8 bk = *(const bf16x8*)&Kl[(ln16 + 16 * nt) * LDT + kc * 32 + quad * 8];
                s[nt] = __builtin_amdgcn_mfma_f32_16x16x32_bf16(aq[kc], bk, s[nt], 0, 0, 0);
            }
        }

        if (!flags || flags[qt * NKT + kt]) {
            const float* mrow = mask + (size_t)(q0 + quad * 4) * SLEN + kt * BC + ln16;
#pragma unroll
            for (int r = 0; r < 4; ++r)
#pragma unroll
                for (int nt = 0; nt < 4; ++nt)
                    s[nt][r] += mrow[(size_t)r * SLEN + nt * 16] * LOG2E;
        }

#pragma unroll
        for (int r = 0; r < 4; ++r) {
            float mx = fmaxf(fmaxf(s[0][r], s[1][r]), fmaxf(s[2][r], s[3][r]));
            mx = fmaxf(mx, __shfl_xor(mx, 1));
            mx = fmaxf(mx, __shfl_xor(mx, 2));
            mx = fmaxf(mx, __shfl_xor(mx, 4));
            mx = fmaxf(mx, __shfl_xor(mx, 8));
            float mnew = fmaxf(m_run[r], mx);
            float alpha = exp2f(m_run[r] - mnew);
            m_run[r] = mnew;
            float rs = 0.f;
#pragma unroll
            for (int nt = 0; nt < 4; ++nt) {
                float p = exp2f(s[nt][r] - mnew);
                s[nt][r] = p;
                rs += p;
            }
            rs += __shfl_xor(rs, 1);
            rs += __shfl_xor(rs, 2);
            rs += __shfl_xor(rs, 4);
            rs += __shfl_xor(rs, 8);
            l_run[r] = l_run[r] * alpha + rs;
#pragma unroll
            for (int dt = 0; dt < 4; ++dt) o[dt][r] *= alpha;
        }

#pragma unroll
        for (int nt = 0; nt < 4; ++nt)
#pragma unroll
            for (int r = 0; r < 4; ++r)
                Pl[(wave * 16 + quad * 4 + r) * LDT + ln16 + 16 * nt] = (bf16)s[nt][r];

#pragma unroll
        for (int kc2 = 0; kc2 < 2; ++kc2) {
            bf16x8 pfr = *(const bf16x8*)&Pl[(wave * 16 + ln16) * LDT + kc2 * 32 + quad * 8];
#pragma unroll
            for (int dt = 0; dt < 4; ++dt) {
                bf16x8 vf = *(const bf16x8*)&Vt[(ln16 + 16 * dt) * LDT + kc2 * 32 + quad * 8];
                o[dt] = __builtin_amdgcn_mfma_f32_16x16x32_bf16(pfr, vf, o[dt], 0, 0, 0);
            }
        }
    }

#pragma unroll
    for (int r = 0; r < 4; ++r) {
        float inv = 1.0f / l_run[r];
        int qrow = q0 + wave * 16 + quad * 4 + r;
        float* orow = out + ((size_t)bh * SLEN + qrow) * DH;
#pragma unroll
        for (int dt = 0; dt < 4; ++dt)
            orow[ln16 + 16 * dt] = o[dt][r] * inv;
    }
}

extern "C" void kernel_launch(void* const* d_in, const int* in_sizes, int n_in,
                              void* d_out, int out_size, void* d_ws, size_t ws_size,
                              hipStream_t stream)
{
    const float* q    = (const float*)d_in[0];
    const float* kv   = (const float*)d_in[1];
    const float* mask = (const float*)d_in[2];
    float* out = (float*)d_out;

    const size_t kvKoff = 4096;                                   // flags: 32*32*4
    const size_t kvToff = kvKoff + (size_t)BH_N * NKT * IMGE_G * 2;
    const size_t need   = kvToff + (size_t)BH_N * NKT * IMGE_G * 2;

    if (ws_size >= need) {
        int*  flags = (int*)d_ws;
        bf16* kvK   = (bf16*)((char*)d_ws + kvKoff);
        bf16* kvT   = (bf16*)((char*)d_ws + kvToff);
        kv_prep<<<dim3(NKT, BH_N), 256, 0, stream>>>(kv, mask, kvK, kvT, flags);
        attn_fwd6<<<dim3(BH_N, SLEN / 128), 512, 0, stream>>>(q, mask, flags, kvK, kvT, out);
    } else {
        int* flags = nullptr;
        if (ws_size >= (size_t)NQT * NKT * sizeof(int)) {
            flags = (int*)d_ws;
            attn_mask_flags<<<dim3(NKT, NQT), 256, 0, stream>>>(mask, flags);
        }
        attn_fwd<<<dim3(NQT, BH_N), 256, 0, stream>>>(q, kv, mask, flags, out);
    }
}